// Round 1
// baseline (417.138 us; speedup 1.0000x reference)
//
#include <hip/hip_runtime.h>
#include <hip/hip_bf16.h>
#include <cstddef>

#define BIGV 10000000.0f
#define WPV  1.0f
#define TEMPV 0.01f
#define INVT 100.0f

// Sizes (fixed by the problem)
#define BATCH 8
#define T1N 256
#define T2N 1024
#define CN 128
#define DN 1279          // T1+T2-1

#define LSTRIDE 132      // LDS row stride in floats (128 + 4 pad, keeps 16B alignment)

// ---------------------------------------------------------------------------
// Kernel 1: skewed cost matrix sk[b][d][j] = mean_c |A[b,j,c] - B[b,clip(d-j),c]|
// Tile: 32 (d) x 32 (j) per block, 256 threads, register micro-tile 2x2.
// ---------------------------------------------------------------------------
__global__ __launch_bounds__(256) void cost_kernel(const float* __restrict__ A,
                                                   const float* __restrict__ Bf,
                                                   float* __restrict__ sk) {
    __shared__ float As[32 * LSTRIDE];   // 16,896 B
    __shared__ float Bs[63 * LSTRIDE];   // 33,264 B  (total 50,160 B < 64 KB)

    const int b  = blockIdx.z;
    const int d0 = blockIdx.y * 32;
    const int j0 = blockIdx.x * 32;
    const int tid = threadIdx.x;

    const float* Ab = A  + (size_t)b * T1N * CN;
    const float* Bb = Bf + (size_t)b * T2N * CN;

    // stage A tile: 32 rows x 128 floats = 1024 float4 -> 4 per thread
    for (int i = 0; i < 4; ++i) {
        int idx = tid + i * 256;          // 0..1023
        int row = idx >> 5;               // /32 float4 per row
        int c4  = (idx & 31) << 2;
        float4 f = *(const float4*)(Ab + (size_t)(j0 + row) * CN + c4);
        *(float4*)&As[row * LSTRIDE + c4] = f;
    }

    // B window rows r = d - j for d in [d0,d0+31], j in [j0,j0+31]:
    // r in [d0-j0-31, d0-j0+31] -> 63 rows, clamped to [0,1023]
    const int rbase = d0 - j0 - 31;
    for (int i = 0; i < 8; ++i) {
        int idx = tid + i * 256;          // need 63*32 = 2016 float4
        if (idx < 2016) {
            int row = idx >> 5;
            int c4  = (idx & 31) << 2;
            int gr = rbase + row;
            gr = gr < 0 ? 0 : (gr > T2N - 1 ? T2N - 1 : gr);
            float4 f = *(const float4*)(Bb + (size_t)gr * CN + c4);
            *(float4*)&Bs[row * LSTRIDE + c4] = f;
        }
    }
    __syncthreads();

    const int tj = tid & 15;    // j = j0 + tj + 16*ji, ji in {0,1}
    const int td = tid >> 4;    // d = d0 + td + 16*dk, dk in {0,1}

    float acc[2][2];
    acc[0][0] = acc[0][1] = acc[1][0] = acc[1][1] = 0.0f;

    const int brow0 = td - tj + 31;  // local row for m = dk - ji = 0

    for (int c = 0; c < CN; c += 4) {
        float4 a4[2], bv[3];
        #pragma unroll
        for (int ji = 0; ji < 2; ++ji)
            a4[ji] = *(const float4*)&As[(tj + 16 * ji) * LSTRIDE + c];
        #pragma unroll
        for (int mm = 0; mm < 3; ++mm)
            bv[mm] = *(const float4*)&Bs[(brow0 + 16 * (mm - 1)) * LSTRIDE + c];
        #pragma unroll
        for (int dk = 0; dk < 2; ++dk) {
            #pragma unroll
            for (int ji = 0; ji < 2; ++ji) {
                float4 aa = a4[ji];
                float4 bb = bv[dk - ji + 1];
                acc[dk][ji] += fabsf(aa.x - bb.x) + fabsf(aa.y - bb.y)
                             + fabsf(aa.z - bb.z) + fabsf(aa.w - bb.w);
            }
        }
    }

    #pragma unroll
    for (int dk = 0; dk < 2; ++dk) {
        int d = d0 + td + 16 * dk;
        if (d < DN) {
            size_t rowoff = ((size_t)b * DN + d) * T1N;
            #pragma unroll
            for (int ji = 0; ji < 2; ++ji) {
                int j = j0 + tj + 16 * ji;
                sk[rowoff + j] = acc[dk][ji] * (1.0f / 128.0f);
            }
        }
    }
}

// ---------------------------------------------------------------------------
// Kernel 2: anti-diagonal soft-DTW DP. One block per batch, thread t owns
// column c = t+1 of the (T1+1)-wide row. Two LDS row buffers rotated.
// ---------------------------------------------------------------------------
__global__ __launch_bounds__(256) void dp_kernel(const float* __restrict__ sk,
                                                 const int* __restrict__ lenA,
                                                 const int* __restrict__ lenB,
                                                 float* __restrict__ partials) {
    const int b = blockIdx.x;
    const int t = threadIdx.x;

    __shared__ float bufA[260];   // starts as R[-2] = pcp0
    __shared__ float bufB[260];   // starts as R[-1] = pc0

    bufA[t + 1] = BIGV;
    bufB[t + 1] = BIGV;
    if (t == 0) { bufA[0] = 0.0f; bufB[0] = BIGV; }

    const int la = lenA[b];
    const int lb = lenB[b];
    const int dEnd = la + lb - 2;     // in [638, 1278]
    const int capT = la - 1;          // column la -> thread la-1

    const float* skb = sk + ((size_t)b * DN) * T1N + t;

    float* P2 = bufA;   // R[d-2]
    float* P1 = bufB;   // R[d-1]

    // depth-2 cost prefetch
    float c0 = skb[0];
    float c1 = skb[T1N];
    __syncthreads();

    for (int d = 0; d <= dEnd; ++d) {
        float cv = c0;
        c0 = c1;
        int dn = d + 2; dn = dn > dEnd ? dEnd : dn;
        c1 = skb[(size_t)dn * T1N];

        float p2  = P2[t];        // R[d-2][c-1]
        float p1b = P1[t];        // R[d-1][c-1]
        float p1a = P1[t + 1];    // R[d-1][c]

        float va = p2;
        float vb = p1a + WPV;
        float vc = p1b + WPV;
        float m = fminf(va, fminf(vb, vc));
        float s = __expf((m - va) * INVT)
                + __expf((m - vb) * INVT)
                + __expf((m - vc) * INVT);
        float v = cv + m - TEMPV * __logf(s);

        __syncthreads();          // all reads of P2/P1 done
        P2[t + 1] = v;            // P2 becomes R[d]
        if (t == 0) P2[0] = BIGV;
        if (d == dEnd && t == capT) partials[b] = v;
        __syncthreads();          // writes visible

        float* tmp = P2; P2 = P1; P1 = tmp;
    }
}

// ---------------------------------------------------------------------------
// Kernel 3: sum the 8 per-batch losses into d_out[0]
// ---------------------------------------------------------------------------
__global__ void reduce_kernel(const float* __restrict__ partials,
                              float* __restrict__ out) {
    if (threadIdx.x == 0) {
        float s = 0.0f;
        for (int i = 0; i < BATCH; ++i) s += partials[i];
        out[0] = s;
    }
}

extern "C" void kernel_launch(void* const* d_in, const int* in_sizes, int n_in,
                              void* d_out, int out_size, void* d_ws, size_t ws_size,
                              hipStream_t stream) {
    const float* feaA = (const float*)d_in[0];
    const int*   lenA = (const int*)d_in[1];
    const float* feaB = (const float*)d_in[2];
    const int*   lenB = (const int*)d_in[3];

    float* sk = (float*)d_ws;                                   // 8*1279*256*4 = 10,477,568 B
    float* partials = (float*)((char*)d_ws + (size_t)BATCH * DN * T1N * sizeof(float));

    // K1: skewed cost. grid: 8 j-tiles x 40 d-tiles x 8 batches
    cost_kernel<<<dim3(T1N / 32, (DN + 31) / 32, BATCH), 256, 0, stream>>>(feaA, feaB, sk);
    // K2: DP, one block per batch
    dp_kernel<<<BATCH, 256, 0, stream>>>(sk, lenA, lenB, partials);
    // K3: final sum
    reduce_kernel<<<1, 64, 0, stream>>>(partials, (float*)d_out);
}